// Round 11
// baseline (245.439 us; speedup 1.0000x reference)
//
#include <hip/hip_runtime.h>
#include <math.h>
#include <stdint.h>

// Problem constants
#define BB    32
#define CIN   64
#define HH    32
#define WW    32
#define COUT  128
#define PP    1024      // HH*WW
#define OTILE 4         // output channels per block
#define PTILE 256       // pixels per block (4 waves x 64 px = 8 rows)
#define NPAD  12        // sorted theta list padded to 12 (3 pairs headroom)
#define TABN  2048      // f-table knots (u in [0,2048), no upper clamp needed)
#define TROW  36        // tile row stride (34 cols + 2 slack)
#define TWSZ  148       // per-wave tile dwords (4*36 + dump + pad)
#define CN    (COUT * NPAD)   // 1536 uint2 per channel in wst

// Log2 domain: Z = (x - theta)*SCALEE, SCALEE = inv_denom*log2(e) = 19.2359
// Table coordinate u = (Z - ZLO)/h = 8Z + 24 = x*MSC8 + thp, thp = 24 - theta*MSC8
static constexpr float  MSC8     = 153.88747102815611f;   // SCALEE * 8
static constexpr double M2Nd     = 0.26359713811572677;   // 2^-SBITS
static constexpr float  OUTSCALE = 2.7025482032898827e-05f; // ALPHA*R*ln2^2
static constexpr float  ZLO      = -3.0f;
static constexpr float  TABH     = 0.125f;
static constexpr float  IDXBIAS  = 24.0f;                 // -ZLO/h
static constexpr float  CUTBIAS  = 4.0f;                  // 24 - 8*ZCUT, ZCUT = 2.5

// ---------------- P0: prescale, pair-split, sort desc, pad ----------------
// ws[(c*COUT + o)*NPAD + j] : (thp f32 bits, ko byte-offset) pairs, thp DESCENDING
__global__ __launch_bounds__(256) void sort_theta_kernel(
    const float* __restrict__ theta, uint2* __restrict__ ws)
{
    int gid = blockIdx.x * 256 + threadIdx.x;   // o*CIN + c (theta layout)
    if (gid >= COUT * CIN) return;
    int o = gid >> 6, c = gid & 63;
    const float* tg = theta + (size_t)gid * 9;
    float    tv[NPAD];
    uint32_t kv[NPAD];
#pragma unroll
    for (int k = 0; k < 9; ++k) {
        tv[k] = fmaf(tg[k], -MSC8, IDXBIAS);              // full-precision thp
        int dy = k / 3, dx = k - 3 * dy;
        kv[k] = (uint32_t)((dy * TROW + dx) * 4);         // BYTE offset into sxi tile
    }
    for (int i = 1; i < 9; ++i) {               // insertion sort DESCENDING by thp
        float    key = tv[i];
        uint32_t kk  = kv[i];
        int j = i - 1;
        while (j >= 0 && tv[j] < key) { tv[j + 1] = tv[j]; kv[j + 1] = kv[j]; --j; }
        tv[j + 1] = key; kv[j + 1] = kk;
    }
    tv[9] = -1e30f; kv[9] = 0;                  // inactive pads: never ballot-active
    tv[10] = -1e30f; kv[10] = 0;
    tv[11] = -1e30f; kv[11] = 0;
    uint2* og = ws + (size_t)(c * COUT + o) * NPAD;
#pragma unroll
    for (int j = 0; j < NPAD; ++j) og[j] = make_uint2(__float_as_uint(tv[j]), kv[j]);
}

// ---------------- P1: per-(b, band, c) cut in thp units ----------------
__global__ __launch_bounds__(256) void bandcut_kernel(
    const float* __restrict__ x, float* __restrict__ bandcut)
{
    int t  = threadIdx.x;
    int bc = blockIdx.x;            // b*CIN + c
    const float4* xp = (const float4*)(x + (size_t)bc * PP);
    float4 v = xp[t];               // thread t: row t>>3, cols 4(t&7)..+3
    float m = fmaxf(fmaxf(v.x, v.y), fmaxf(v.z, v.w));
    m = fmaxf(m, __shfl_xor(m, 1));
    m = fmaxf(m, __shfl_xor(m, 2));
    m = fmaxf(m, __shfl_xor(m, 4));   // 8 threads of a row hold rowmax
    __shared__ float rmax[32];
    if ((t & 7) == 0) rmax[t >> 3] = m;
    __syncthreads();
    if (t < 16) {
        int r0 = max(2 * t - 1, 0), r3 = min(2 * t + 2, 31);
        float mm = rmax[r0];
        for (int r = r0 + 1; r <= r3; ++r) mm = fmaxf(mm, rmax[r]);
        mm = fmaxf(mm, 0.0f);         // zero-pad contributes xi = 0
        int b = bc >> 6, c = bc & 63;
        bandcut[((b * 16 + t) << 6) + c] = fmaf(mm, -MSC8, CUTBIAS);
    }
}

// ---------------- P2: coefficient table, fp64-evaluated ----------------
// tab[i] = (c0, c1) with f(u) ~= c0 + c1*u on [i, i+1]. Segment 0 is ZEROED:
// u<0 taps saturate to index 0 via v_cvt_u32_f32 and contribute exactly 0.
// Table covers u in [0, 2048): max reachable u ~1500, so no upper clamp.
__global__ __launch_bounds__(256) void ftable_kernel(float2* __restrict__ tab)
{
    int i = blockIdx.x * 256 + threadIdx.x;
    if (i >= TABN) return;
    if (i == 0) { tab[0] = make_float2(0.0f, 0.0f); return; }
    double Z0 = (double)ZLO + (double)TABH * i;
    double Z1 = Z0 + (double)TABH;
    auto fd = [](double Z) {
        double E = exp2(Z);
        double a = log2(1.0 + E);
        double b = log2(1.0 + E * M2Nd);
        return a * a - b * b;
    };
    double y0 = fd(Z0), y1 = fd(Z1);
    double c1 = y1 - y0;                 // per-u slope (segment width = 1 u)
    double c0 = y0 - (double)i * c1;
    tab[i] = make_float2((float)c0, (float)c1);
}

// ---------------- main kernel ----------------
// R11 = R10 (SGPR-batched pairs + wave-uniform branch chain) + two cuts:
// (a) odd-count tail: np2 = cnt>>1 full pairs, plus ONE single-tap epilogue
//     when cnt is odd, its SGPR pair picked by a scalar 5-way select (SALU
//     pipe, no VALU slots). Pad taps are never evaluated any more (~7% of
//     tap work at ~50% odd-rate).
// (b) dual accumulators a0/a1: same instruction count, half the per-tap
//     dependent chain; merged in the epilogue.
__global__ __launch_bounds__(256) void nlconv_kernel(
    const float* __restrict__ x,        // [B, CIN, 32, 32]
    const uint2* __restrict__ wst,      // sorted (thp, ko4) pairs [c][o][NPAD]
    const float* __restrict__ wcut,     // cutp [b][band][c]
    const float2* __restrict__ ftabg,   // coefficient table
    float* __restrict__ out)            // [B, COUT, 32, 32]
{
    __shared__ float  sxi[4 * TWSZ];    // per-wave 4x36 halo tiles + dump, 2368 B
    __shared__ float2 ftab[TABN];       // 16 KiB

    const int t  = threadIdx.x;
    const int b  = blockIdx.x;
    const int pt = blockIdx.y;
    const int ot = blockIdx.z;
    const int w  = t >> 6;
    const int l  = t & 63;
    const int o0 = ot * OTILE;
    const int band = pt * 4 + w;
    const int rl = l >> 5, col = l & 31;

#pragma unroll
    for (int k = 0; k < TABN / 256; ++k) ftab[t + 256 * k] = ftabg[t + 256 * k];

    // per-lane staging map: 3 entries e = l, l+64, l+128 over the 144-dword tile
    const int wbase = w * TWSZ;
    int   gofs[3];   // dword offset within a channel's 1024-px image
    float msc[3];    // MSC8 or 0 (halo/invalid)
    int   laddr[3];  // dword index into sxi
#pragma unroll
    for (int i = 0; i < 3; ++i) {
        int e  = l + 64 * i;
        bool valid = (e < 144);
        int ec = valid ? e : 144;           // dump slot for invalid third entries
        int r  = ec / TROW;
        int tc = ec - r * TROW;
        int grow = band * 2 - 1 + r;
        int gcol = tc - 1;
        bool inter = valid && (grow >= 0) && (grow < HH) && (gcol >= 0) && (gcol < WW) && (r < 4);
        gofs[i]  = (min(max(grow, 0), HH - 1) << 5) + min(max(gcol, 0), WW - 1);
        msc[i]   = inter ? MSC8 : 0.0f;
        laddr[i] = wbase + min(ec, TWSZ - 1);
    }

    // this wave's 64 channel cuts: lane c holds cutp[c]
    const float vcut = wcut[(size_t)((b * 16 + band) << 6) + l];

    // ballot source: lane l owns pair l (g = l/12, j = l%12) of the block's
    // 48-pair slice; lanes 48..63 duplicate 47 (pad, never ballot-active)
    const int spl = min(l, OTILE * NPAD - 1);

    const float* xc0 = x + (size_t)b * CIN * PP;
    const uint2* wso = wst + (size_t)o0 * NPAD;  // + c*CN
    const char*  sxb = (const char*)sxi + ((wbase + rl * TROW + col) << 2);  // body x base (bytes)

    float accA[OTILE], accB[OTILE];
#pragma unroll
    for (int i = 0; i < OTILE; ++i) { accA[i] = 0.0f; accB[i] = 0.0f; }

    // prologue: xv(0) -> tile(0); xv <- c=1; pr(c=0) -> fth; pr <- c=1
    float xv[3];
#pragma unroll
    for (int i = 0; i < 3; ++i) xv[i] = xc0[gofs[i]] * msc[i];
    uint2 pr = wso[spl];                          // c=0 pair (thp in .x)
#pragma unroll
    for (int i = 0; i < 3; ++i) sxi[laddr[i]] = xv[i];
    float fth = __uint_as_float(pr.x);
#pragma unroll
    for (int i = 0; i < 3; ++i) xv[i] = xc0[PP + gofs[i]] * msc[i];
    pr = wso[(size_t)CN + spl];                   // c=1 in flight (vmcnt)

    __syncthreads();   // ftab ready (x tiles are wave-private)

    for (int c = 0; c < CIN; ++c) {
        const float cutp = __uint_as_float(
            (uint32_t)__builtin_amdgcn_readlane((int)__float_as_uint(vcut), c));
        unsigned long long mA = __ballot(fth > cutp);   // bit l = pair l active

        const uint2* thc = wso + (size_t)c * CN;

#pragma unroll
        for (int g = 0; g < OTILE; ++g) {
            // batched scalar load of the group's pair list (72 B used),
            // materialized BEFORE the branch chain (asm fence)
            const uint4* gth = (const uint4*)(thc + g * NPAD);
            uint4 P0 = gth[0], P1 = gth[1], P2 = gth[2], P3 = gth[3];
            uint2 P4 = *(const uint2*)(gth + 4);          // tap 8 only
            asm volatile("" :: "s"(P0.x), "s"(P1.x), "s"(P2.x), "s"(P3.x), "s"(P4.x));
            int cnt = (int)__popcll(mA & (0xFFFull << (12 * g)));  // <= 9
            int np2 = cnt >> 1;                // full pairs (<=4), WAVE-UNIFORM
            int odd = cnt & 1;
            float a0 = accA[g], a1 = accB[g];
            // tap: 6 VALU + 2 DS, pairs from SGPRs (free operands).
            // v_cvt_u32_f32 saturates u<0 -> seg 0 (zeroed); no clamps.
#define TAPH(TH, KO)                                                   \
            {                                                          \
                float xa = *(const float*)(sxb + (KO));                \
                float u  = xa + __uint_as_float(TH);                   \
                uint32_t ii;                                           \
                asm("v_cvt_u32_f32_e32 %0, %1" : "=v"(ii) : "v"(u));   \
                float2 cf = ftab[ii];                                  \
                a0 += cf.x;                                            \
                a1 = fmaf(cf.y, u, a1);                                \
            }
#define PAIRT(P) { TAPH((P).x, (P).y) TAPH((P).z, (P).w) }
            if (np2 > 0) { PAIRT(P0);
            if (np2 > 1) { PAIRT(P1);
            if (np2 > 2) { PAIRT(P2);
            if (np2 > 3) { PAIRT(P3); }}}}
            if (odd) {
                // single odd tap at pair index np2: scalar 5-way select
                uint32_t th = P0.x, ko = P0.y;
                if (np2 == 1) { th = P1.x; ko = P1.y; }
                if (np2 == 2) { th = P2.x; ko = P2.y; }
                if (np2 == 3) { th = P3.x; ko = P3.y; }
                if (np2 == 4) { th = P4.x; ko = P4.y; }
                TAPH(th, ko)
            }
#undef PAIRT
#undef TAPH
            accA[g] = a0; accB[g] = a1;
        }

        // stage tile(c+1) from xv; roll fth; prefetch xv/pr for c+2
#pragma unroll
        for (int i = 0; i < 3; ++i) sxi[laddr[i]] = xv[i];
        fth = __uint_as_float(pr.x);
        {
            int c2 = min(c + 2, CIN - 1);
            const float* xcn = xc0 + (size_t)c2 * PP;
#pragma unroll
            for (int i = 0; i < 3; ++i) xv[i] = xcn[gofs[i]] * msc[i];
            pr = wso[(size_t)c2 * CN + spl];
        }
    }

    float* ob = out + ((size_t)b * COUT + o0) * PP + pt * PTILE + t;
#pragma unroll
    for (int o = 0; o < OTILE; ++o) {
        float v = (accA[o] + accB[o]) * OUTSCALE;
        v = fminf(fmaxf(v, 0.0f), 9.0f);
        ob[(size_t)o * PP] = v;
    }
}

extern "C" void kernel_launch(void* const* d_in, const int* in_sizes, int n_in,
                              void* d_out, int out_size, void* d_ws, size_t ws_size,
                              hipStream_t stream) {
    const float* x     = (const float*)d_in[0];  // [32,64,32,32]
    const float* theta = (const float*)d_in[1];  // [128,64,3,3]
    float* out         = (float*)d_out;          // [32,128,32,32]

    uint2*  ws_theta = (uint2*)d_ws;                                 // 786,432 B (+16 pad)
    float*  ws_cut   = (float*)(ws_theta + (size_t)CIN * COUT * NPAD + 2);  // 131,072 B
    float2* ws_tab   = (float2*)(ws_cut + (size_t)BB * 16 * 64);     //  16,384 B

    sort_theta_kernel<<<dim3((COUT * CIN + 255) / 256), dim3(256), 0, stream>>>(theta, ws_theta);
    bandcut_kernel<<<dim3(BB * CIN), dim3(256), 0, stream>>>(x, ws_cut);
    ftable_kernel<<<dim3(TABN / 256), dim3(256), 0, stream>>>(ws_tab);

    dim3 grid(BB, PP / PTILE, COUT / OTILE);     // 32 x 4 x 32 = 4096 blocks
    nlconv_kernel<<<grid, dim3(256), 0, stream>>>(x, ws_theta, ws_cut, ws_tab, out);
}

// Round 12
// 240.455 us; speedup vs baseline: 1.0207x; 1.0207x over previous
//
#include <hip/hip_runtime.h>
#include <math.h>
#include <stdint.h>

// Problem constants
#define BB    32
#define CIN   64
#define HH    32
#define WW    32
#define COUT  128
#define PP    1024      // HH*WW
#define OTILE 4         // output channels per block
#define PTILE 256       // pixels per block (4 waves x 64 px = 8 rows)
#define NPAD  12        // sorted theta list padded to 12 (3 pairs headroom)
#define TABN  2048      // f-table knots (u in [0,2048), no upper clamp needed)
#define TROW  36        // tile row stride (34 cols + 2 slack)
#define TWSZ  148       // per-wave tile dwords (4*36 + dump + pad)
#define CN    (COUT * NPAD)   // 1536 uint2 per channel in wst

typedef float v2f __attribute__((ext_vector_type(2)));

// Log2 domain: Z = (x - theta)*SCALEE, SCALEE = inv_denom*log2(e) = 19.2359
// Table coordinate u = (Z - ZLO)/h = 8Z + 24 = x*MSC8 + thp, thp = 24 - theta*MSC8
static constexpr float  MSC8     = 153.88747102815611f;   // SCALEE * 8
static constexpr double M2Nd     = 0.26359713811572677;   // 2^-SBITS
static constexpr float  OUTSCALE = 2.7025482032898827e-05f; // ALPHA*R*ln2^2
static constexpr float  ZLO      = -3.0f;
static constexpr float  TABH     = 0.125f;
static constexpr float  IDXBIAS  = 24.0f;                 // -ZLO/h
static constexpr float  CUTBIAS  = 4.0f;                  // 24 - 8*ZCUT, ZCUT = 2.5

// ---------------- P0: prescale, pair-split, sort desc, pad ----------------
// ws[(c*COUT + o)*NPAD + j] : (thp f32 bits, ko byte-offset) pairs, thp DESCENDING
__global__ __launch_bounds__(256) void sort_theta_kernel(
    const float* __restrict__ theta, uint2* __restrict__ ws)
{
    int gid = blockIdx.x * 256 + threadIdx.x;   // o*CIN + c (theta layout)
    if (gid >= COUT * CIN) return;
    int o = gid >> 6, c = gid & 63;
    const float* tg = theta + (size_t)gid * 9;
    float    tv[NPAD];
    uint32_t kv[NPAD];
#pragma unroll
    for (int k = 0; k < 9; ++k) {
        tv[k] = fmaf(tg[k], -MSC8, IDXBIAS);              // full-precision thp
        int dy = k / 3, dx = k - 3 * dy;
        kv[k] = (uint32_t)((dy * TROW + dx) * 4);         // BYTE offset into sxi tile
    }
    for (int i = 1; i < 9; ++i) {               // insertion sort DESCENDING by thp
        float    key = tv[i];
        uint32_t kk  = kv[i];
        int j = i - 1;
        while (j >= 0 && tv[j] < key) { tv[j + 1] = tv[j]; kv[j + 1] = kv[j]; --j; }
        tv[j + 1] = key; kv[j + 1] = kk;
    }
    tv[9] = -1e30f; kv[9] = 0;                  // inactive pads: u -> huge negative -> seg 0
    tv[10] = -1e30f; kv[10] = 0;
    tv[11] = -1e30f; kv[11] = 0;
    uint2* og = ws + (size_t)(c * COUT + o) * NPAD;
#pragma unroll
    for (int j = 0; j < NPAD; ++j) og[j] = make_uint2(__float_as_uint(tv[j]), kv[j]);
}

// ---------------- P1: per-(b, band, c) cut in thp units ----------------
__global__ __launch_bounds__(256) void bandcut_kernel(
    const float* __restrict__ x, float* __restrict__ bandcut)
{
    int t  = threadIdx.x;
    int bc = blockIdx.x;            // b*CIN + c
    const float4* xp = (const float4*)(x + (size_t)bc * PP);
    float4 v = xp[t];               // thread t: row t>>3, cols 4(t&7)..+3
    float m = fmaxf(fmaxf(v.x, v.y), fmaxf(v.z, v.w));
    m = fmaxf(m, __shfl_xor(m, 1));
    m = fmaxf(m, __shfl_xor(m, 2));
    m = fmaxf(m, __shfl_xor(m, 4));   // 8 threads of a row hold rowmax
    __shared__ float rmax[32];
    if ((t & 7) == 0) rmax[t >> 3] = m;
    __syncthreads();
    if (t < 16) {
        int r0 = max(2 * t - 1, 0), r3 = min(2 * t + 2, 31);
        float mm = rmax[r0];
        for (int r = r0 + 1; r <= r3; ++r) mm = fmaxf(mm, rmax[r]);
        mm = fmaxf(mm, 0.0f);         // zero-pad contributes xi = 0
        int b = bc >> 6, c = bc & 63;
        bandcut[((b * 16 + t) << 6) + c] = fmaf(mm, -MSC8, CUTBIAS);
    }
}

// ---------------- P2: coefficient table, fp64-evaluated ----------------
// tab[i] = (c0, c1) with f(u) ~= c0 + c1*u on [i, i+1]. Segment 0 is ZEROED:
// u<0 taps saturate to index 0 via v_cvt_u32_f32 and contribute exactly 0.
// Table covers u in [0, 2048): max reachable u ~1500, so no upper clamp.
__global__ __launch_bounds__(256) void ftable_kernel(float2* __restrict__ tab)
{
    int i = blockIdx.x * 256 + threadIdx.x;
    if (i >= TABN) return;
    if (i == 0) { tab[0] = make_float2(0.0f, 0.0f); return; }
    double Z0 = (double)ZLO + (double)TABH * i;
    double Z1 = Z0 + (double)TABH;
    auto fd = [](double Z) {
        double E = exp2(Z);
        double a = log2(1.0 + E);
        double b = log2(1.0 + E * M2Nd);
        return a * a - b * b;
    };
    double y0 = fd(Z0), y1 = fd(Z1);
    double c1 = y1 - y0;                 // per-u slope (segment width = 1 u)
    double c0 = y0 - (double)i * c1;
    tab[i] = make_float2((float)c0, (float)c1);
}

// ---------------- main kernel ----------------
// R12 = R10 (SGPR-batched pairs + wave-uniform round-up pair chain, the
// measured-best branch structure) with ONE change: the per-tap accumulate
// (v_fmac + v_add, 2 VALU) is fused into a single v_pk_fma_f32.
//   acc2 = (sum c0, sum c1*u);  mul2 = (1.0, u);  cf = (c0, c1) from one
//   ds_read_b64 (already an aligned VGPR pair).
//   acc2 = pk_fma(cf, mul2, acc2)   // .x += c0*1.0 ; .y += c1*u
// Tap body: 5 VALU + 2 DS (was 6+2). Also splits the accumulate dependency
// into two independent 2-op chains (the R11 dual-acc idea, without its
// branch-structure regression). Pad taps in the round-up pair still hit the
// zeroed segment 0 and add exactly 0 to both halves.
__global__ __launch_bounds__(256) void nlconv_kernel(
    const float* __restrict__ x,        // [B, CIN, 32, 32]
    const uint2* __restrict__ wst,      // sorted (thp, ko4) pairs [c][o][NPAD]
    const float* __restrict__ wcut,     // cutp [b][band][c]
    const float2* __restrict__ ftabg,   // coefficient table
    float* __restrict__ out)            // [B, COUT, 32, 32]
{
    __shared__ float  sxi[4 * TWSZ];    // per-wave 4x36 halo tiles + dump, 2368 B
    __shared__ float2 ftab[TABN];       // 16 KiB

    const int t  = threadIdx.x;
    const int b  = blockIdx.x;
    const int pt = blockIdx.y;
    const int ot = blockIdx.z;
    const int w  = t >> 6;
    const int l  = t & 63;
    const int o0 = ot * OTILE;
    const int band = pt * 4 + w;
    const int rl = l >> 5, col = l & 31;

#pragma unroll
    for (int k = 0; k < TABN / 256; ++k) ftab[t + 256 * k] = ftabg[t + 256 * k];

    // per-lane staging map: 3 entries e = l, l+64, l+128 over the 144-dword tile
    const int wbase = w * TWSZ;
    int   gofs[3];   // dword offset within a channel's 1024-px image
    float msc[3];    // MSC8 or 0 (halo/invalid)
    int   laddr[3];  // dword index into sxi
#pragma unroll
    for (int i = 0; i < 3; ++i) {
        int e  = l + 64 * i;
        bool valid = (e < 144);
        int ec = valid ? e : 144;           // dump slot for invalid third entries
        int r  = ec / TROW;
        int tc = ec - r * TROW;
        int grow = band * 2 - 1 + r;
        int gcol = tc - 1;
        bool inter = valid && (grow >= 0) && (grow < HH) && (gcol >= 0) && (gcol < WW) && (r < 4);
        gofs[i]  = (min(max(grow, 0), HH - 1) << 5) + min(max(gcol, 0), WW - 1);
        msc[i]   = inter ? MSC8 : 0.0f;
        laddr[i] = wbase + min(ec, TWSZ - 1);
    }

    // this wave's 64 channel cuts: lane c holds cutp[c]
    const float vcut = wcut[(size_t)((b * 16 + band) << 6) + l];

    // ballot source: lane l owns pair l (g = l/12, j = l%12) of the block's
    // 48-pair slice; lanes 48..63 duplicate 47 (masked out of every group)
    const int spl = min(l, OTILE * NPAD - 1);

    const float* xc0 = x + (size_t)b * CIN * PP;
    const uint2* wso = wst + (size_t)o0 * NPAD;  // + c*CN
    const char*  sxb = (const char*)sxi + ((wbase + rl * TROW + col) << 2);  // body x base (bytes)

    v2f acc2[OTILE];
#pragma unroll
    for (int i = 0; i < OTILE; ++i) acc2[i] = (v2f)(0.0f);

    v2f mul2;
    mul2.x = 1.0f;      // constant half: pk_fma .x lane accumulates c0*1.0
    mul2.y = 0.0f;

    // prologue: xv(0) -> tile(0); xv <- c=1; pr(c=0) -> fth; pr <- c=1
    float xv[3];
#pragma unroll
    for (int i = 0; i < 3; ++i) xv[i] = xc0[gofs[i]] * msc[i];
    uint2 pr = wso[spl];                          // c=0 pair (thp in .x)
#pragma unroll
    for (int i = 0; i < 3; ++i) sxi[laddr[i]] = xv[i];
    float fth = __uint_as_float(pr.x);
#pragma unroll
    for (int i = 0; i < 3; ++i) xv[i] = xc0[PP + gofs[i]] * msc[i];
    pr = wso[(size_t)CN + spl];                   // c=1 in flight (vmcnt)

    __syncthreads();   // ftab ready (x tiles are wave-private)

    for (int c = 0; c < CIN; ++c) {
        const float cutp = __uint_as_float(
            (uint32_t)__builtin_amdgcn_readlane((int)__float_as_uint(vcut), c));
        unsigned long long mA = __ballot(fth > cutp);   // bit l = pair l active

        const uint2* thc = wso + (size_t)c * CN;

#pragma unroll
        for (int g = 0; g < OTILE; ++g) {
            // batched scalar load of the whole group's pair list (80 B),
            // materialized BEFORE the branch chain (asm fence)
            const uint4* gth = (const uint4*)(thc + g * NPAD);
            uint4 P0 = gth[0], P1 = gth[1], P2 = gth[2], P3 = gth[3], P4 = gth[4];
            asm volatile("" :: "s"(P0.x), "s"(P1.x), "s"(P2.x), "s"(P3.x), "s"(P4.x));
            int cnt = (int)__popcll(mA & (0xFFFull << (12 * g)));
            int np = (cnt + 1) >> 1;           // pair count (<=5), WAVE-UNIFORM
            v2f a2 = acc2[g];
            // tap: 5 VALU + 2 DS. v_cvt_u32_f32 saturates u<0 -> seg 0
            // (zeroed); pk_fma fuses both accumulates into one instruction.
#define TAPH(TH, KO)                                                   \
            {                                                          \
                float xa = *(const float*)(sxb + (KO));                \
                mul2.y = xa + __uint_as_float(TH);                     \
                uint32_t ii;                                           \
                asm("v_cvt_u32_f32_e32 %0, %1" : "=v"(ii) : "v"(mul2.y)); \
                v2f cf = *(const v2f*)&ftab[ii];                       \
                asm("v_pk_fma_f32 %0, %1, %2, %0"                      \
                    : "+v"(a2) : "v"(cf), "v"(mul2));                  \
            }
#define PAIRT(P) { TAPH((P).x, (P).y) TAPH((P).z, (P).w) }
            if (np > 0) { PAIRT(P0);
            if (np > 1) { PAIRT(P1);
            if (np > 2) { PAIRT(P2);
            if (np > 3) { PAIRT(P3);
            if (np > 4) { PAIRT(P4); }}}}}
#undef PAIRT
#undef TAPH
            acc2[g] = a2;
        }

        // stage tile(c+1) from xv; roll fth; prefetch xv/pr for c+2
#pragma unroll
        for (int i = 0; i < 3; ++i) sxi[laddr[i]] = xv[i];
        fth = __uint_as_float(pr.x);
        {
            int c2 = min(c + 2, CIN - 1);
            const float* xcn = xc0 + (size_t)c2 * PP;
#pragma unroll
            for (int i = 0; i < 3; ++i) xv[i] = xcn[gofs[i]] * msc[i];
            pr = wso[(size_t)c2 * CN + spl];
        }
    }

    float* ob = out + ((size_t)b * COUT + o0) * PP + pt * PTILE + t;
#pragma unroll
    for (int o = 0; o < OTILE; ++o) {
        float v = (acc2[o].x + acc2[o].y) * OUTSCALE;
        v = fminf(fmaxf(v, 0.0f), 9.0f);
        ob[(size_t)o * PP] = v;
    }
}

extern "C" void kernel_launch(void* const* d_in, const int* in_sizes, int n_in,
                              void* d_out, int out_size, void* d_ws, size_t ws_size,
                              hipStream_t stream) {
    const float* x     = (const float*)d_in[0];  // [32,64,32,32]
    const float* theta = (const float*)d_in[1];  // [128,64,3,3]
    float* out         = (float*)d_out;          // [32,128,32,32]

    uint2*  ws_theta = (uint2*)d_ws;                                 // 786,432 B (+16 pad)
    float*  ws_cut   = (float*)(ws_theta + (size_t)CIN * COUT * NPAD + 2);  // 131,072 B
    float2* ws_tab   = (float2*)(ws_cut + (size_t)BB * 16 * 64);     //  16,384 B

    sort_theta_kernel<<<dim3((COUT * CIN + 255) / 256), dim3(256), 0, stream>>>(theta, ws_theta);
    bandcut_kernel<<<dim3(BB * CIN), dim3(256), 0, stream>>>(x, ws_cut);
    ftable_kernel<<<dim3(TABN / 256), dim3(256), 0, stream>>>(ws_tab);

    dim3 grid(BB, PP / PTILE, COUT / OTILE);     // 32 x 4 x 32 = 4096 blocks
    nlconv_kernel<<<grid, dim3(256), 0, stream>>>(x, ws_theta, ws_cut, ws_tab, out);
}

// Round 13
// 227.945 us; speedup vs baseline: 1.0767x; 1.0549x over previous
//
#include <hip/hip_runtime.h>
#include <math.h>
#include <stdint.h>

// Problem constants
#define BB    32
#define CIN   64
#define HH    32
#define WW    32
#define COUT  128
#define PP    1024      // HH*WW
#define OTILE 4         // output channels per block
#define PTILE 256       // pixels per block (4 waves x 64 px = 8 rows)
#define NPAD  12        // sorted theta list padded to 12 (3 pairs headroom)
#define TABN  2048      // f-table knots (u in [0,2048), no upper clamp needed)
#define TROW  36        // tile row stride (34 cols + 2 slack)
#define TWSZ  148       // per-wave tile dwords (4*36 + dump + pad)
#define CN    (COUT * NPAD)   // 1536 uint2 per channel in wst

// Log2 domain: Z = (x - theta)*SCALEE, SCALEE = inv_denom*log2(e) = 19.2359
// Table coordinate u = (Z - ZLO)/h = 8Z + 24 = x*MSC8 + thp, thp = 24 - theta*MSC8
static constexpr float  MSC8     = 153.88747102815611f;   // SCALEE * 8
static constexpr double M2Nd     = 0.26359713811572677;   // 2^-SBITS
static constexpr float  OUTSCALE = 2.7025482032898827e-05f; // ALPHA*R*ln2^2
static constexpr float  ZLO      = -3.0f;
static constexpr float  TABH     = 0.125f;
static constexpr float  IDXBIAS  = 24.0f;                 // -ZLO/h
static constexpr float  CUTBIAS  = 4.0f;                  // 24 - 8*ZCUT, ZCUT = 2.5

// ---------------- P0: prescale, pair-split, sort desc, pad ----------------
// ws[(c*COUT + o)*NPAD + j] : (thp f32 bits, ko byte-offset) pairs, thp DESCENDING
__global__ __launch_bounds__(256) void sort_theta_kernel(
    const float* __restrict__ theta, uint2* __restrict__ ws)
{
    int gid = blockIdx.x * 256 + threadIdx.x;   // o*CIN + c (theta layout)
    if (gid >= COUT * CIN) return;
    int o = gid >> 6, c = gid & 63;
    const float* tg = theta + (size_t)gid * 9;
    float    tv[NPAD];
    uint32_t kv[NPAD];
#pragma unroll
    for (int k = 0; k < 9; ++k) {
        tv[k] = fmaf(tg[k], -MSC8, IDXBIAS);              // full-precision thp
        int dy = k / 3, dx = k - 3 * dy;
        kv[k] = (uint32_t)((dy * TROW + dx) * 4);         // BYTE offset into sxi tile
    }
    for (int i = 1; i < 9; ++i) {               // insertion sort DESCENDING by thp
        float    key = tv[i];
        uint32_t kk  = kv[i];
        int j = i - 1;
        while (j >= 0 && tv[j] < key) { tv[j + 1] = tv[j]; kv[j + 1] = kv[j]; --j; }
        tv[j + 1] = key; kv[j + 1] = kk;
    }
    tv[9] = -1e30f; kv[9] = 0;                  // inactive pads: u -> huge negative -> seg 0
    tv[10] = -1e30f; kv[10] = 0;
    tv[11] = -1e30f; kv[11] = 0;
    uint2* og = ws + (size_t)(c * COUT + o) * NPAD;
#pragma unroll
    for (int j = 0; j < NPAD; ++j) og[j] = make_uint2(__float_as_uint(tv[j]), kv[j]);
}

// ---------------- P1: per-(b, band, c) cut in thp units ----------------
__global__ __launch_bounds__(256) void bandcut_kernel(
    const float* __restrict__ x, float* __restrict__ bandcut)
{
    int t  = threadIdx.x;
    int bc = blockIdx.x;            // b*CIN + c
    const float4* xp = (const float4*)(x + (size_t)bc * PP);
    float4 v = xp[t];               // thread t: row t>>3, cols 4(t&7)..+3
    float m = fmaxf(fmaxf(v.x, v.y), fmaxf(v.z, v.w));
    m = fmaxf(m, __shfl_xor(m, 1));
    m = fmaxf(m, __shfl_xor(m, 2));
    m = fmaxf(m, __shfl_xor(m, 4));   // 8 threads of a row hold rowmax
    __shared__ float rmax[32];
    if ((t & 7) == 0) rmax[t >> 3] = m;
    __syncthreads();
    if (t < 16) {
        int r0 = max(2 * t - 1, 0), r3 = min(2 * t + 2, 31);
        float mm = rmax[r0];
        for (int r = r0 + 1; r <= r3; ++r) mm = fmaxf(mm, rmax[r]);
        mm = fmaxf(mm, 0.0f);         // zero-pad contributes xi = 0
        int b = bc >> 6, c = bc & 63;
        bandcut[((b * 16 + t) << 6) + c] = fmaf(mm, -MSC8, CUTBIAS);
    }
}

// ---------------- P2: coefficient table, fp64-evaluated ----------------
// tab[i] = (c0, c1) with f(u) ~= c0 + c1*u on [i, i+1]. Segment 0 is ZEROED:
// u<0 taps saturate to index 0 via v_cvt_u32_f32 and contribute exactly 0.
// Table covers u in [0, 2048): max reachable u ~1500, so no upper clamp.
__global__ __launch_bounds__(256) void ftable_kernel(float2* __restrict__ tab)
{
    int i = blockIdx.x * 256 + threadIdx.x;
    if (i >= TABN) return;
    if (i == 0) { tab[0] = make_float2(0.0f, 0.0f); return; }
    double Z0 = (double)ZLO + (double)TABH * i;
    double Z1 = Z0 + (double)TABH;
    auto fd = [](double Z) {
        double E = exp2(Z);
        double a = log2(1.0 + E);
        double b = log2(1.0 + E * M2Nd);
        return a * a - b * b;
    };
    double y0 = fd(Z0), y1 = fd(Z1);
    double c1 = y1 - y0;                 // per-u slope (segment width = 1 u)
    double c0 = y0 - (double)i * c1;
    tab[i] = make_float2((float)c0, (float)c1);
}

// ---------------- main kernel ----------------
// R13 = R10 (SGPR-batched pairs + wave-uniform round-up pair chain — the
// measured-best structure, 183.5us) with ONE minimal change: dual
// accumulators. a0 += c0 and a1 = fmaf(c1, u, a1) are two INDEPENDENT 2-op
// chains instead of R10's serial fmaf->add 4-op chain per tap. Zero extra
// instructions, zero branch changes, zero shared registers (each tap keeps
// its private u/cf regs so the scheduler can still overlap taps — the
// lesson from R12's pk_fma failure). Merged once in the epilogue.
__global__ __launch_bounds__(256) void nlconv_kernel(
    const float* __restrict__ x,        // [B, CIN, 32, 32]
    const uint2* __restrict__ wst,      // sorted (thp, ko4) pairs [c][o][NPAD]
    const float* __restrict__ wcut,     // cutp [b][band][c]
    const float2* __restrict__ ftabg,   // coefficient table
    float* __restrict__ out)            // [B, COUT, 32, 32]
{
    __shared__ float  sxi[4 * TWSZ];    // per-wave 4x36 halo tiles + dump, 2368 B
    __shared__ float2 ftab[TABN];       // 16 KiB

    const int t  = threadIdx.x;
    const int b  = blockIdx.x;
    const int pt = blockIdx.y;
    const int ot = blockIdx.z;
    const int w  = t >> 6;
    const int l  = t & 63;
    const int o0 = ot * OTILE;
    const int band = pt * 4 + w;
    const int rl = l >> 5, col = l & 31;

#pragma unroll
    for (int k = 0; k < TABN / 256; ++k) ftab[t + 256 * k] = ftabg[t + 256 * k];

    // per-lane staging map: 3 entries e = l, l+64, l+128 over the 144-dword tile
    const int wbase = w * TWSZ;
    int   gofs[3];   // dword offset within a channel's 1024-px image
    float msc[3];    // MSC8 or 0 (halo/invalid)
    int   laddr[3];  // dword index into sxi
#pragma unroll
    for (int i = 0; i < 3; ++i) {
        int e  = l + 64 * i;
        bool valid = (e < 144);
        int ec = valid ? e : 144;           // dump slot for invalid third entries
        int r  = ec / TROW;
        int tc = ec - r * TROW;
        int grow = band * 2 - 1 + r;
        int gcol = tc - 1;
        bool inter = valid && (grow >= 0) && (grow < HH) && (gcol >= 0) && (gcol < WW) && (r < 4);
        gofs[i]  = (min(max(grow, 0), HH - 1) << 5) + min(max(gcol, 0), WW - 1);
        msc[i]   = inter ? MSC8 : 0.0f;
        laddr[i] = wbase + min(ec, TWSZ - 1);
    }

    // this wave's 64 channel cuts: lane c holds cutp[c]
    const float vcut = wcut[(size_t)((b * 16 + band) << 6) + l];

    // ballot source: lane l owns pair l (g = l/12, j = l%12) of the block's
    // 48-pair slice; lanes 48..63 duplicate 47 (masked out of every group)
    const int spl = min(l, OTILE * NPAD - 1);

    const float* xc0 = x + (size_t)b * CIN * PP;
    const uint2* wso = wst + (size_t)o0 * NPAD;  // + c*CN
    const char*  sxb = (const char*)sxi + ((wbase + rl * TROW + col) << 2);  // body x base (bytes)

    float accA[OTILE], accB[OTILE];
#pragma unroll
    for (int i = 0; i < OTILE; ++i) { accA[i] = 0.0f; accB[i] = 0.0f; }

    // prologue: xv(0) -> tile(0); xv <- c=1; pr(c=0) -> fth; pr <- c=1
    float xv[3];
#pragma unroll
    for (int i = 0; i < 3; ++i) xv[i] = xc0[gofs[i]] * msc[i];
    uint2 pr = wso[spl];                          // c=0 pair (thp in .x)
#pragma unroll
    for (int i = 0; i < 3; ++i) sxi[laddr[i]] = xv[i];
    float fth = __uint_as_float(pr.x);
#pragma unroll
    for (int i = 0; i < 3; ++i) xv[i] = xc0[PP + gofs[i]] * msc[i];
    pr = wso[(size_t)CN + spl];                   // c=1 in flight (vmcnt)

    __syncthreads();   // ftab ready (x tiles are wave-private)

    for (int c = 0; c < CIN; ++c) {
        const float cutp = __uint_as_float(
            (uint32_t)__builtin_amdgcn_readlane((int)__float_as_uint(vcut), c));
        unsigned long long mA = __ballot(fth > cutp);   // bit l = pair l active

        const uint2* thc = wso + (size_t)c * CN;

#pragma unroll
        for (int g = 0; g < OTILE; ++g) {
            // batched scalar load of the whole group's pair list (80 B),
            // materialized BEFORE the branch chain (asm fence)
            const uint4* gth = (const uint4*)(thc + g * NPAD);
            uint4 P0 = gth[0], P1 = gth[1], P2 = gth[2], P3 = gth[3], P4 = gth[4];
            asm volatile("" :: "s"(P0.x), "s"(P1.x), "s"(P2.x), "s"(P3.x), "s"(P4.x));
            int cnt = (int)__popcll(mA & (0xFFFull << (12 * g)));
            int np = (cnt + 1) >> 1;           // pair count (<=5), WAVE-UNIFORM
            float a0 = accA[g], a1 = accB[g];
            // tap: 6 VALU + 2 DS, pairs from SGPRs (free operands).
            // v_cvt_u32_f32 saturates u<0 -> seg 0 (zeroed); no clamps.
            // Dual acc: two independent 2-op chains per tap (vs one 4-op).
#define TAPH(TH, KO)                                                   \
            {                                                          \
                float xa = *(const float*)(sxb + (KO));                \
                float u  = xa + __uint_as_float(TH);                   \
                uint32_t ii;                                           \
                asm("v_cvt_u32_f32_e32 %0, %1" : "=v"(ii) : "v"(u));   \
                float2 cf = ftab[ii];                                  \
                a0 += cf.x;                                            \
                a1 = fmaf(cf.y, u, a1);                                \
            }
#define PAIRT(P) { TAPH((P).x, (P).y) TAPH((P).z, (P).w) }
            if (np > 0) { PAIRT(P0);
            if (np > 1) { PAIRT(P1);
            if (np > 2) { PAIRT(P2);
            if (np > 3) { PAIRT(P3);
            if (np > 4) { PAIRT(P4); }}}}}
#undef PAIRT
#undef TAPH
            accA[g] = a0; accB[g] = a1;
        }

        // stage tile(c+1) from xv; roll fth; prefetch xv/pr for c+2
#pragma unroll
        for (int i = 0; i < 3; ++i) sxi[laddr[i]] = xv[i];
        fth = __uint_as_float(pr.x);
        {
            int c2 = min(c + 2, CIN - 1);
            const float* xcn = xc0 + (size_t)c2 * PP;
#pragma unroll
            for (int i = 0; i < 3; ++i) xv[i] = xcn[gofs[i]] * msc[i];
            pr = wso[(size_t)c2 * CN + spl];
        }
    }

    float* ob = out + ((size_t)b * COUT + o0) * PP + pt * PTILE + t;
#pragma unroll
    for (int o = 0; o < OTILE; ++o) {
        float v = (accA[o] + accB[o]) * OUTSCALE;
        v = fminf(fmaxf(v, 0.0f), 9.0f);
        ob[(size_t)o * PP] = v;
    }
}

extern "C" void kernel_launch(void* const* d_in, const int* in_sizes, int n_in,
                              void* d_out, int out_size, void* d_ws, size_t ws_size,
                              hipStream_t stream) {
    const float* x     = (const float*)d_in[0];  // [32,64,32,32]
    const float* theta = (const float*)d_in[1];  // [128,64,3,3]
    float* out         = (float*)d_out;          // [32,128,32,32]

    uint2*  ws_theta = (uint2*)d_ws;                                 // 786,432 B (+16 pad)
    float*  ws_cut   = (float*)(ws_theta + (size_t)CIN * COUT * NPAD + 2);  // 131,072 B
    float2* ws_tab   = (float2*)(ws_cut + (size_t)BB * 16 * 64);     //  16,384 B

    sort_theta_kernel<<<dim3((COUT * CIN + 255) / 256), dim3(256), 0, stream>>>(theta, ws_theta);
    bandcut_kernel<<<dim3(BB * CIN), dim3(256), 0, stream>>>(x, ws_cut);
    ftable_kernel<<<dim3(TABN / 256), dim3(256), 0, stream>>>(ws_tab);

    dim3 grid(BB, PP / PTILE, COUT / OTILE);     // 32 x 4 x 32 = 4096 blocks
    nlconv_kernel<<<grid, dim3(256), 0, stream>>>(x, ws_theta, ws_cut, ws_tab, out);
}